// Round 12
// baseline (245.459 us; speedup 1.0000x reference)
//
#include <hip/hip_runtime.h>
#include <hip/hip_bf16.h>
#include <math.h>

#define DMODEL 512
#define NHEAD  8
#define DHEAD  64

typedef __attribute__((ext_vector_type(8))) short bf16x8;
typedef __attribute__((ext_vector_type(4))) float f32x4;
typedef __attribute__((ext_vector_type(4))) short short4v;

static __device__ inline short f2bf(float f) {
    __hip_bfloat16 h = __float2bfloat16(f);
    return *reinterpret_cast<short*>(&h);
}

#define GLOAD_LDS16(gp, lp)                                                      \
    __builtin_amdgcn_global_load_lds(                                            \
        (const __attribute__((address_space(1))) unsigned int*)(gp),             \
        (__attribute__((address_space(3))) unsigned int*)(lp), 16, 0, 0)

// ============================ batched fp32 -> bf16 convert ============================
struct CvtArgs {
    const float* src[12];
    short*       dst[12];
    int          n[12];
    int          start[12];   // exclusive prefix of per-slot block counts
};

__global__ __launch_bounds__(256) void cvt_kernel(CvtArgs args) {
    int bid = blockIdx.x;
    int t = 0;
    while (t < 11 && bid >= args.start[t + 1]) ++t;
    int idx = ((bid - args.start[t]) * 256 + threadIdx.x) * 8;
    if (idx >= args.n[t]) return;
    const float* s = args.src[t] + idx;
    float4 a = *(const float4*)s;
    float4 b = *(const float4*)(s + 4);
    bf16x8 o;
    o[0] = f2bf(a.x); o[1] = f2bf(a.y); o[2] = f2bf(a.z); o[3] = f2bf(a.w);
    o[4] = f2bf(b.x); o[5] = f2bf(b.y); o[6] = f2bf(b.z); o[7] = f2bf(b.w);
    *(bf16x8*)(args.dst[t] + idx) = o;
}

// ============================ bf16 MFMA GEMM (multi-job, optional fused LayerNorm) ====
// Round-6 config (64x64 tile, 4 waves, dbuf 2-phase, XCD swizzle) + per-job
// lnA flag fusing LayerNorm into A-staging. Each wave computes stats (same
// 8-elem/lane + butterfly as the old ln_kernel -> bit-identical mu,r) for its
// 16 staging rows, held in lanes 0..15 (no LDS). A-staging becomes f32
// reg-load -> normalize -> ds_write_b128 into the SAME swizzled layout.
// Removes the 3 standalone LN dispatches and the qn16 round-trip.
struct GJobs {
    const short* A[3];
    const float* Af[3];     // f32 A when lnA
    const float* lngm[3];
    const float* lnbt[3];
    const short* W[3];
    const float* bias[3];
    const float* resid[3];
    void*        C[3];
    int M[3], N[3], K[3];
    float scale[3];
    int relu[3], obf[3], lnA[3], nblk[3];
};

__global__ __launch_bounds__(256) void gemm_bf16(GJobs jb) {
    __shared__ short As[2][64 * 64];   // 16 KB
    __shared__ short Bs[2][64 * 64];   // 16 KB

    int bid = blockIdx.x, j = 0;
    while (j < 2 && bid >= jb.nblk[j]) { bid -= jb.nblk[j]; ++j; }
    const short* __restrict__ A  = jb.A[j];
    const float* __restrict__ Af = jb.Af[j];
    const float* __restrict__ lng = jb.lngm[j];
    const float* __restrict__ lnbv = jb.lnbt[j];
    const short* __restrict__ W = jb.W[j];
    const int N = jb.N[j], K = jb.K[j];
    const int lnA = jb.lnA[j];
    {
        int nb = jb.nblk[j];
        if ((nb & 7) == 0) bid = (bid & 7) * (nb >> 3) + (bid >> 3);
    }
    const int nbx = N >> 6;
    const int tn = (bid % nbx) * 64;
    const int tm = (bid / nbx) * 64;

    const int tid  = threadIdx.x;
    const int w    = tid >> 6;
    const int l    = tid & 63;
    const int lq   = l & 15;
    const int g    = l >> 4;
    const int wm   = (w >> 1) * 32;
    const int wn   = (w & 1) * 32;
    const int lrow = l >> 3;
    const int lsl  = l & 7;

    // ---- fused-LN row stats: wave w owns rows w*8+0..7 (lanes 0-7) and
    //      32+w*8+0..7 (lanes 8-15). K==512 for all lnA jobs. ----
    float myMu = 0.f, myR = 0.f;
    if (lnA) {
#pragma unroll 4
        for (int jr = 0; jr < 16; ++jr) {
            int row = (jr < 8) ? (w * 8 + jr) : (32 + w * 8 + (jr - 8));
            const float* x = Af + (size_t)(tm + row) * K + l * 8;
            float4 a = *(const float4*)x;
            float4 b2 = *(const float4*)(x + 4);
            float s = a.x + a.y + a.z + a.w + b2.x + b2.y + b2.z + b2.w;
            float q = a.x*a.x + a.y*a.y + a.z*a.z + a.w*a.w
                    + b2.x*b2.x + b2.y*b2.y + b2.z*b2.z + b2.w*b2.w;
#pragma unroll
            for (int off = 1; off < 64; off <<= 1) {
                s += __shfl_xor(s, off);
                q += __shfl_xor(q, off);
            }
            float mu  = s * (1.0f / 512.f);
            float var = q * (1.0f / 512.f) - mu * mu;
            float rr  = rsqrtf(var + 1e-6f);
            if (l == jr) { myMu = mu; myR = rr; }
        }
    }

    auto stageA_ln = [&](int nb, int k0n) {
        const int slot = lsl ^ lrow;           // (row&7)==lrow for both rows
        float mu0 = __shfl(myMu, lrow),     rr0 = __shfl(myR, lrow);
        float mu1 = __shfl(myMu, 8 + lrow), rr1 = __shfl(myR, 8 + lrow);
        float4 g0 = *(const float4*)(lng  + k0n + slot * 8);
        float4 g1 = *(const float4*)(lng  + k0n + slot * 8 + 4);
        float4 c0 = *(const float4*)(lnbv + k0n + slot * 8);
        float4 c1 = *(const float4*)(lnbv + k0n + slot * 8 + 4);
#pragma unroll
        for (int i = 0; i < 2; ++i) {
            int row = i * 32 + w * 8 + lrow;
            const float* x = Af + (size_t)(tm + row) * K + k0n + slot * 8;
            float4 a = *(const float4*)x;
            float4 b2 = *(const float4*)(x + 4);
            float mu = i ? mu1 : mu0, rr = i ? rr1 : rr0;
            bf16x8 o;
            o[0] = f2bf((a.x  - mu) * rr * g0.x + c0.x);
            o[1] = f2bf((a.y  - mu) * rr * g0.y + c0.y);
            o[2] = f2bf((a.z  - mu) * rr * g0.z + c0.z);
            o[3] = f2bf((a.w  - mu) * rr * g0.w + c0.w);
            o[4] = f2bf((b2.x - mu) * rr * g1.x + c1.x);
            o[5] = f2bf((b2.y - mu) * rr * g1.y + c1.y);
            o[6] = f2bf((b2.z - mu) * rr * g1.z + c1.z);
            o[7] = f2bf((b2.w - mu) * rr * g1.w + c1.w);
            *(bf16x8*)&As[nb][i * 2048 + w * 512 + l * 8] = o;
        }
    };

    f32x4 acc[2][2];
#pragma unroll
    for (int i = 0; i < 2; ++i)
#pragma unroll
        for (int jj = 0; jj < 2; ++jj)
            acc[i][jj] = (f32x4){0.f, 0.f, 0.f, 0.f};

    const int nkt = K >> 6;

    // ---- prologue: stage tile 0 into buffer 0 ----
    if (lnA) {
        stageA_ln(0, 0);
    } else {
#pragma unroll
        for (int i = 0; i < 2; ++i) {
            int row = i * 32 + w * 8 + lrow;
            int slot = lsl ^ (row & 7);
            GLOAD_LDS16(A + (size_t)(tm + row) * K + slot * 8,
                        &As[0][i * 2048 + w * 512]);
        }
    }
#pragma unroll
    for (int i = 0; i < 2; ++i) {
        int row = i * 32 + w * 8 + lrow;
        int slot = lsl ^ (row & 7);
        GLOAD_LDS16(W + (size_t)(tn + row) * K + slot * 8,
                    &Bs[0][i * 2048 + w * 512]);
    }

#pragma unroll 2
    for (int kt = 0; kt < nkt; ++kt) {
        const int cur = kt & 1;
        __syncthreads();
        if (kt + 1 < nkt) {
            const int k0n = (kt + 1) * 64;
            if (lnA) {
                stageA_ln(cur ^ 1, k0n);
            } else {
#pragma unroll
                for (int i = 0; i < 2; ++i) {
                    int row = i * 32 + w * 8 + lrow;
                    int slot = lsl ^ (row & 7);
                    GLOAD_LDS16(A + (size_t)(tm + row) * K + k0n + slot * 8,
                                &As[cur ^ 1][i * 2048 + w * 512]);
                }
            }
#pragma unroll
            for (int i = 0; i < 2; ++i) {
                int row = i * 32 + w * 8 + lrow;
                int slot = lsl ^ (row & 7);
                GLOAD_LDS16(W + (size_t)(tn + row) * K + k0n + slot * 8,
                            &Bs[cur ^ 1][i * 2048 + w * 512]);
            }
        }

#pragma unroll
        for (int ks = 0; ks < 2; ++ks) {
            const int sl = ((ks * 4 + g) ^ (lq & 7)) * 8;
            bf16x8 af[2], bfv[2];
#pragma unroll
            for (int i = 0; i < 2; ++i) {
                af[i]  = *(const bf16x8*)&As[cur][(wm + i * 16 + lq) * 64 + sl];
                bfv[i] = *(const bf16x8*)&Bs[cur][(wn + i * 16 + lq) * 64 + sl];
            }
#pragma unroll
            for (int i = 0; i < 2; ++i)
#pragma unroll
                for (int jj = 0; jj < 2; ++jj)
                    acc[i][jj] = __builtin_amdgcn_mfma_f32_16x16x32_bf16(
                        af[i], bfv[jj], acc[i][jj], 0, 0, 0);
        }
    }

    const float* bias  = jb.bias[j];
    const float* resid = jb.resid[j];
    const float scale  = jb.scale[j];
    const int relu = jb.relu[j], obf = jb.obf[j];
#pragma unroll
    for (int i = 0; i < 2; ++i) {
#pragma unroll
        for (int r = 0; r < 4; ++r) {
            int row = tm + wm + i * 16 + g * 4 + r;
#pragma unroll
            for (int jj = 0; jj < 2; ++jj) {
                int col = tn + wn + jj * 16 + lq;
                float v = acc[i][jj][r] * scale;
                if (bias)  v += bias[col];
                if (resid) v += resid[(size_t)row * N + col];
                if (relu)  v = fmaxf(v, 0.f);
                if (obf) ((short*)jb.C[j])[(size_t)row * N + col] = f2bf(v);
                else     ((float*)jb.C[j])[(size_t)row * N + col] = v;
            }
        }
    }
}

// ============================ MFMA flash attention (in-block K-split + XCD affinity) ==
// Round-10 kernel (best measured): in-block K-split, LDS combine, XCD-affine
// work remap (all 16 q-strips of one bh share lin%8 -> same XCD -> KV L2-hot).
__global__ __launch_bounds__(512) void attn_mfma_kernel(
        const short* __restrict__ Q, const short* __restrict__ K,
        const short* __restrict__ V, short* __restrict__ O,
        int Lq, int Lk, int causal, int qs, int kvs) {
    __shared__ short Kt[2][64 * 64];     // per-group [key][d] swizzled, 8 KB each
    __shared__ short Vt[2][64][72];      // per-group [d][key], 9 KB each
    __shared__ short Pb[8][16][72];      // per-wave P tile, 18 KB (reused as f32 Ox/Lx)

    const int tid  = threadIdx.x;
    const int wave = tid >> 6;           // 0..7
    const int wq4  = wave & 3;           // q-tile within the 64-q strip
    const int tsel = wave >> 2;          // key-parity group
    const int lane = tid & 63;
    const int lq   = lane & 15;
    const int g    = lane >> 4;
    // ---- XCD-affinity remap (bijective on 16x32 grid) ----
    const int lin = (int)(blockIdx.x + blockIdx.y * gridDim.x);
    const int bh  = (lin & 7) * 4 + ((lin >> 3) & 3);
    const int qst = lin >> 5;            // 0..15
    const int b = bh >> 3, h = bh & 7;
    const int qx = causal ? ((int)gridDim.x - 1 - qst) : qst;
    const int q0 = qx * 64 + wq4 * 16;
    const float NEG = -__builtin_inff();

    size_t qoff = (size_t)(b * Lq + q0 + lq) * qs + h * DHEAD;
    bf16x8 qf0 = *(const bf16x8*)(Q + qoff + g * 8);
    bf16x8 qf1 = *(const bf16x8*)(Q + qoff + 32 + g * 8);

    f32x4 o[4] = {{0,0,0,0},{0,0,0,0},{0,0,0,0},{0,0,0,0}};
    f32x4 lacc = {0.f, 0.f, 0.f, 0.f};

    bf16x8 ones;
    {
        short ov = (lq == 0) ? (short)0x3F80 : (short)0;
#pragma unroll
        for (int i = 0; i < 8; ++i) ones[i] = ov;
    }

    const int nkt = causal ? (qx + 1) : (Lk >> 6);   // block-uniform
    const int npair = (nkt + 1) >> 1;
    const int lrow = lane >> 3;
    const int lsl  = lane & 7;
    const int gt = tid & 255;            // group-local tid
    const int va = gt & 31;              // V staging: key pair index
    const int vd = (gt >> 5) * 8;        // V staging: d chunk

#pragma unroll 1
    for (int kp = 0; kp < npair; ++kp) {
        const int t = 2 * kp + tsel;     // this group's key tile
        const int active = (t < nkt);    // wave-uniform
        __syncthreads();
        if (active) {
#pragma unroll
            for (int i = 0; i < 2; ++i) {
                int row = i * 32 + wq4 * 8 + lrow;
                int slot = lsl ^ (row & 7);
                GLOAD_LDS16(K + (size_t)(b * Lk + t * 64 + row) * kvs + h * DHEAD + slot * 8,
                            &Kt[tsel][i * 2048 + wq4 * 512]);
            }
            size_t gb = (size_t)(b * Lk + t * 64 + 2 * va) * kvs + h * DHEAD + vd;
            bf16x8 v0 = *(const bf16x8*)(V + gb);
            bf16x8 v1 = *(const bf16x8*)(V + gb + kvs);
#pragma unroll
            for (int i = 0; i < 8; ++i) {
                unsigned p = (unsigned short)v0[i] | ((unsigned)(unsigned short)v1[i] << 16);
                *(unsigned*)&Vt[tsel][vd + i][2 * va] = p;
            }
        }
        __syncthreads();
        if (!active) continue;

        // ---- S^T = K Q^T ----
        f32x4 s[4];
#pragma unroll
        for (int sub = 0; sub < 4; ++sub) {
            int rr = sub * 16 + lq;
            const int sl0 = ((0 + g) ^ (lq & 7)) * 8;
            const int sl1 = ((4 + g) ^ (lq & 7)) * 8;
            bf16x8 kf0 = *(const bf16x8*)&Kt[tsel][rr * 64 + sl0];
            bf16x8 kf1 = *(const bf16x8*)&Kt[tsel][rr * 64 + sl1];
            f32x4 a = {0.f, 0.f, 0.f, 0.f};
            a = __builtin_amdgcn_mfma_f32_16x16x32_bf16(kf0, qf0, a, 0, 0, 0);
            a = __builtin_amdgcn_mfma_f32_16x16x32_bf16(kf1, qf1, a, 0, 0, 0);
            s[sub] = a;
        }
        if (causal && t == nkt - 1) {
            int qg = q0 + lq;
#pragma unroll
            for (int sub = 0; sub < 4; ++sub) {
#pragma unroll
                for (int r = 0; r < 4; ++r) {
                    int kg = t * 64 + sub * 16 + g * 4 + r;
                    if (kg > qg) s[sub][r] = NEG;
                }
            }
        }

        // ---- exp + packed P write ----
#pragma unroll
        for (int sub = 0; sub < 4; ++sub) {
            short4v p4;
            p4.x = f2bf(__expf(fminf(s[sub][0], 60.f)));
            p4.y = f2bf(__expf(fminf(s[sub][1], 60.f)));
            p4.z = f2bf(__expf(fminf(s[sub][2], 60.f)));
            p4.w = f2bf(__expf(fminf(s[sub][3], 60.f)));
            *(short4v*)&Pb[wave][lq][sub * 16 + g * 4] = p4;
        }
        bf16x8 pf0 = *(const bf16x8*)&Pb[wave][lq][g * 8];
        bf16x8 pf1 = *(const bf16x8*)&Pb[wave][lq][32 + g * 8];

        // ---- O += P V ; l += P @ ones ----
#pragma unroll
        for (int dc = 0; dc < 4; ++dc) {
            bf16x8 vf0 = *(const bf16x8*)&Vt[tsel][dc * 16 + lq][g * 8];
            bf16x8 vf1 = *(const bf16x8*)&Vt[tsel][dc * 16 + lq][32 + g * 8];
            o[dc] = __builtin_amdgcn_mfma_f32_16x16x32_bf16(pf0, vf0, o[dc], 0, 0, 0);
            o[dc] = __builtin_amdgcn_mfma_f32_16x16x32_bf16(pf1, vf1, o[dc], 0, 0, 0);
        }
        lacc = __builtin_amdgcn_mfma_f32_16x16x32_bf16(pf0, ones, lacc, 0, 0, 0);
        lacc = __builtin_amdgcn_mfma_f32_16x16x32_bf16(pf1, ones, lacc, 0, 0, 0);
    }

    // ---- cross-group combine through LDS (Pb retired), then store ----
    float* Ox = (float*)&Pb[0][0][0];      // 4 tiles x 16 q x 64 d = 16 KB
    float* Lx = Ox + 4 * 16 * 64;          // 64 floats
    __syncthreads();                       // all compute/P-reads done
    if (tsel == 1) {
#pragma unroll
        for (int r = 0; r < 4; ++r) {
            int row = g * 4 + r;
            float* dst = Ox + (wq4 * 16 + row) * 64;
            dst[lq]      = o[0][r];
            dst[16 + lq] = o[1][r];
            dst[32 + lq] = o[2][r];
            dst[48 + lq] = o[3][r];
            if (lq == 0) Lx[wq4 * 16 + row] = lacc[r];
        }
    }
    __syncthreads();
    if (tsel == 0) {
#pragma unroll
        for (int r = 0; r < 4; ++r) {
            int row = g * 4 + r;
            float lr = __shfl(lacc[r], g << 4) + Lx[wq4 * 16 + row];
            float inv = 1.f / lr;
            const float* srcx = Ox + (wq4 * 16 + row) * 64;
            size_t ob = (size_t)(b * Lq + q0 + row) * qs + h * DHEAD + lq;
            O[ob + 0]  = f2bf((o[0][r] + srcx[lq])      * inv);
            O[ob + 16] = f2bf((o[1][r] + srcx[16 + lq]) * inv);
            O[ob + 32] = f2bf((o[2][r] + srcx[32 + lq]) * inv);
            O[ob + 48] = f2bf((o[3][r] + srcx[48 + lq]) * inv);
        }
    }
}

// ============================ Launch ============================
static void launch_gemm(GJobs& jb, int njobs, hipStream_t stream) {
    int total = 0;
    for (int i = 0; i < 3; ++i) { if (i >= njobs) jb.nblk[i] = 0; total += jb.nblk[i]; }
    gemm_bf16<<<total, 256, 0, stream>>>(jb);
}

extern "C" void kernel_launch(void* const* d_in, const int* in_sizes, int n_in,
                              void* d_out, int out_size, void* d_ws, size_t ws_size,
                              hipStream_t stream) {
    const float* dec       = (const float*)d_in[0];
    const float* enc       = (const float*)d_in[1];
    const float* slf_Wq    = (const float*)d_in[3];
    const float* slf_Wk    = (const float*)d_in[4];
    const float* slf_Wv    = (const float*)d_in[5];
    const float* slf_Wfc   = (const float*)d_in[6];
    const float* slf_ln_g  = (const float*)d_in[7];
    const float* slf_ln_b  = (const float*)d_in[8];
    const float* enc_Wq    = (const float*)d_in[9];
    const float* enc_Wk    = (const float*)d_in[10];
    const float* enc_Wv    = (const float*)d_in[11];
    const float* enc_Wfc   = (const float*)d_in[12];
    const float* enc_ln_g  = (const float*)d_in[13];
    const float* enc_ln_b  = (const float*)d_in[14];
    const float* ffn_W1    = (const float*)d_in[15];
    const float* ffn_b1    = (const float*)d_in[16];
    const float* ffn_W2    = (const float*)d_in[17];
    const float* ffn_b2    = (const float*)d_in[18];
    const float* ffn_ln_g  = (const float*)d_in[19];
    const float* ffn_ln_b  = (const float*)d_in[20];
    float* out = (float*)d_out;

    const int Bb = 4, L = 1024, M = Bb * L;
    const size_t NE = (size_t)M * DMODEL;          // 2M
    const int WQN = NHEAD * DHEAD * DMODEL;        // 262144
    float* ws = (float*)d_ws;
    float* x1 = ws;
    float* x2 = ws + NE;
    short* kv16e = (short*)x2;     // alias: kv16e consumed (attn2) before x2 written
    short* sb = (short*)(ws + 2 * NE);
    short* dec16 = sb;               sb += NE;
    short* enc16 = sb;               sb += NE;
    short* q16   = sb;               sb += NE;
    short* ao16  = sb;               sb += NE;
    short* kv16  = sb;               sb += 2 * NE;
    short* h16   = sb;               sb += NE / 2;
    short* wq_s  = sb;               sb += WQN;
    short* wkv_s = sb;               sb += 2 * WQN;
    short* wfc_s = sb;               sb += WQN;
    short* wq_e  = sb;               sb += WQN;
    short* wkv_e = sb;               sb += 2 * WQN;
    short* wfc_e = sb;               sb += WQN;
    short* w1_16 = sb;               sb += 256 * DMODEL;
    short* w2_16 = sb;               sb += DMODEL * 256;

    CvtArgs ca;
    ca.src[0] = dec;     ca.dst[0] = dec16;         ca.n[0] = (int)NE;
    ca.src[1] = enc;     ca.dst[1] = enc16;         ca.n[1] = (int)NE;
    ca.src[2] = slf_Wq;  ca.dst[2] = wq_s;          ca.n[2] = WQN;
    ca.src[3] = slf_Wk;  ca.dst[3] = wkv_s;         ca.n[3] = WQN;
    ca.src[4] = slf_Wv;  ca.dst[4] = wkv_s + WQN;   ca.n[4] = WQN;
    ca.src[5] = slf_Wfc; ca.dst[5] = wfc_s;         ca.n[5] = WQN;
    ca.src[6] = enc_Wq;  ca.dst[6] = wq_e;          ca.n[6] = WQN;
    ca.src[7] = enc_Wk;  ca.dst[7] = wkv_e;         ca.n[7] = WQN;
    ca.src[8] = enc_Wv;  ca.dst[8] = wkv_e + WQN;   ca.n[8] = WQN;
    ca.src[9] = enc_Wfc; ca.dst[9] = wfc_e;         ca.n[9] = WQN;
    ca.src[10] = ffn_W1; ca.dst[10] = w1_16;        ca.n[10] = 256 * DMODEL;
    ca.src[11] = ffn_W2; ca.dst[11] = w2_16;        ca.n[11] = DMODEL * 256;
    {
        int acc = 0;
        for (int t = 0; t < 12; ++t) { ca.start[t] = acc; acc += ca.n[t] / 2048; }
        cvt_kernel<<<acc, 256, 0, stream>>>(ca);
    }

    dim3 attn_grid(L / 64, Bb * NHEAD);
    const int NB512  = (M / 64) * (512 / 64);    // 512
    const int NB1024 = (M / 64) * (1024 / 64);   // 1024
    const int NB256  = (M / 64) * (256 / 64);    // 256

    // ---- fused {LN1+Q_self, KV_self, KV_cross} ----
    {
        GJobs jb = {};
        jb.Af[0] = dec; jb.lngm[0] = slf_ln_g; jb.lnbt[0] = slf_ln_b; jb.lnA[0] = 1;
        jb.W[0] = wq_s;  jb.C[0] = q16;
        jb.M[0] = M; jb.N[0] = 512;  jb.K[0] = 512; jb.scale[0] = 0.125f;
        jb.obf[0] = 1; jb.nblk[0] = NB512;
        jb.A[1] = dec16; jb.W[1] = wkv_s; jb.C[1] = kv16;
        jb.M[1] = M; jb.N[1] = 1024; jb.K[1] = 512; jb.scale[1] = 1.f;
        jb.obf[1] = 1; jb.nblk[1] = NB1024;
        jb.A[2] = enc16; jb.W[2] = wkv_e; jb.C[2] = kv16e;
        jb.M[2] = M; jb.N[2] = 1024; jb.K[2] = 512; jb.scale[2] = 1.f;
        jb.obf[2] = 1; jb.nblk[2] = NB1024;
        launch_gemm(jb, 3, stream);
    }
    attn_mfma_kernel<<<attn_grid, 512, 0, stream>>>(q16, kv16, kv16 + 512, ao16,
                                                    L, L, 1, DMODEL, 1024);
    {
        GJobs jb = {};
        jb.A[0] = ao16; jb.W[0] = wfc_s; jb.resid[0] = dec; jb.C[0] = x1;
        jb.M[0] = M; jb.N[0] = 512; jb.K[0] = 512; jb.scale[0] = 1.f;
        jb.obf[0] = 0; jb.nblk[0] = NB512;
        launch_gemm(jb, 1, stream);
    }

    // ---- cross attention (LN2 fused into Q projection) ----
    {
        GJobs jb = {};
        jb.Af[0] = x1; jb.lngm[0] = enc_ln_g; jb.lnbt[0] = enc_ln_b; jb.lnA[0] = 1;
        jb.W[0] = wq_e; jb.C[0] = q16;
        jb.M[0] = M; jb.N[0] = 512; jb.K[0] = 512; jb.scale[0] = 0.125f;
        jb.obf[0] = 1; jb.nblk[0] = NB512;
        launch_gemm(jb, 1, stream);
    }
    attn_mfma_kernel<<<attn_grid, 512, 0, stream>>>(q16, kv16e, kv16e + 512, ao16,
                                                    L, L, 0, DMODEL, 1024);
    {
        GJobs jb = {};
        jb.A[0] = ao16; jb.W[0] = wfc_e; jb.resid[0] = x1; jb.C[0] = x2;
        jb.M[0] = M; jb.N[0] = 512; jb.K[0] = 512; jb.scale[0] = 1.f;
        jb.obf[0] = 0; jb.nblk[0] = NB512;
        launch_gemm(jb, 1, stream);
    }

    // ---- FFN (LN3 fused into W1 GEMM) ----
    {
        GJobs jb = {};
        jb.Af[0] = x2; jb.lngm[0] = ffn_ln_g; jb.lnbt[0] = ffn_ln_b; jb.lnA[0] = 1;
        jb.W[0] = w1_16; jb.bias[0] = ffn_b1; jb.C[0] = h16;
        jb.M[0] = M; jb.N[0] = 256; jb.K[0] = 512; jb.scale[0] = 1.f;
        jb.relu[0] = 1; jb.obf[0] = 1; jb.nblk[0] = NB256;
        launch_gemm(jb, 1, stream);
    }
    {
        GJobs jb = {};
        jb.A[0] = h16; jb.W[0] = w2_16; jb.bias[0] = ffn_b2; jb.resid[0] = x2;
        jb.C[0] = out;
        jb.M[0] = M; jb.N[0] = 512; jb.K[0] = 256; jb.scale[0] = 1.f;
        jb.obf[0] = 0; jb.nblk[0] = NB512;
        launch_gemm(jb, 1, stream);
    }
}

// Round 13
// 233.116 us; speedup vs baseline: 1.0529x; 1.0529x over previous
//
#include <hip/hip_runtime.h>
#include <hip/hip_bf16.h>
#include <math.h>

#define DMODEL 512
#define NHEAD  8
#define DHEAD  64

typedef __attribute__((ext_vector_type(8))) short bf16x8;
typedef __attribute__((ext_vector_type(4))) float f32x4;
typedef __attribute__((ext_vector_type(4))) short short4v;

static __device__ inline short f2bf(float f) {
    __hip_bfloat16 h = __float2bfloat16(f);
    return *reinterpret_cast<short*>(&h);
}

#define GLOAD_LDS16(gp, lp)                                                      \
    __builtin_amdgcn_global_load_lds(                                            \
        (const __attribute__((address_space(1))) unsigned int*)(gp),             \
        (__attribute__((address_space(3))) unsigned int*)(lp), 16, 0, 0)

// ============================ batched fp32 -> bf16 convert ============================
struct CvtArgs {
    const float* src[12];
    short*       dst[12];
    int          n[12];
    int          start[12];   // exclusive prefix of per-slot block counts
};

__global__ __launch_bounds__(256) void cvt_kernel(CvtArgs args) {
    int bid = blockIdx.x;
    int t = 0;
    while (t < 11 && bid >= args.start[t + 1]) ++t;
    int idx = ((bid - args.start[t]) * 256 + threadIdx.x) * 8;
    if (idx >= args.n[t]) return;
    const float* s = args.src[t] + idx;
    float4 a = *(const float4*)s;
    float4 b = *(const float4*)(s + 4);
    bf16x8 o;
    o[0] = f2bf(a.x); o[1] = f2bf(a.y); o[2] = f2bf(a.z); o[3] = f2bf(a.w);
    o[4] = f2bf(b.x); o[5] = f2bf(b.y); o[6] = f2bf(b.z); o[7] = f2bf(b.w);
    *(bf16x8*)(args.dst[t] + idx) = o;
}

// ============================ LayerNorm (fp32 in, bf16 out) ============================
__global__ __launch_bounds__(256) void ln_kernel(const float* __restrict__ X,
                                                 const float* __restrict__ gam,
                                                 const float* __restrict__ bet,
                                                 short* __restrict__ Y) {
    int row = blockIdx.x * 4 + (threadIdx.x >> 6);
    int tid = threadIdx.x & 63;
    const float* x = X + (size_t)row * DMODEL;
    float4 a = *(const float4*)(x + tid * 4);
    float4 b = *(const float4*)(x + 256 + tid * 4);
    float sum = a.x + a.y + a.z + a.w + b.x + b.y + b.z + b.w;
    float sq  = a.x*a.x + a.y*a.y + a.z*a.z + a.w*a.w
              + b.x*b.x + b.y*b.y + b.z*b.z + b.w*b.w;
#pragma unroll
    for (int off = 1; off < 64; off <<= 1) {
        sum += __shfl_xor(sum, off);
        sq  += __shfl_xor(sq, off);
    }
    float mu  = sum * (1.0f / DMODEL);
    float var = sq * (1.0f / DMODEL) - mu * mu;
    float r   = rsqrtf(var + 1e-6f);

    float4 g1 = *(const float4*)(gam + tid * 4);
    float4 c1 = *(const float4*)(bet + tid * 4);
    float4 g2 = *(const float4*)(gam + 256 + tid * 4);
    float4 c2 = *(const float4*)(bet + 256 + tid * 4);
    short4v y1, y2;
    y1.x = f2bf((a.x - mu) * r * g1.x + c1.x);
    y1.y = f2bf((a.y - mu) * r * g1.y + c1.y);
    y1.z = f2bf((a.z - mu) * r * g1.z + c1.z);
    y1.w = f2bf((a.w - mu) * r * g1.w + c1.w);
    y2.x = f2bf((b.x - mu) * r * g2.x + c2.x);
    y2.y = f2bf((b.y - mu) * r * g2.y + c2.y);
    y2.z = f2bf((b.z - mu) * r * g2.z + c2.z);
    y2.w = f2bf((b.w - mu) * r * g2.w + c2.w);
    short* y = Y + (size_t)row * DMODEL;
    *(short4v*)(y + tid * 4)       = y1;
    *(short4v*)(y + 256 + tid * 4) = y2;
}

// ============================ bf16 MFMA GEMM (multi-job) ============================
// Round-6 config (best measured): 64x64 tile, 4 waves 32x32, double-buffered
// LDS 2-phase pipeline + bijective within-job XCD swizzle.
struct GJobs {
    const short* A[3];
    const short* W[3];
    const float* bias[3];
    const float* resid[3];
    void*        C[3];
    int M[3], N[3], K[3];
    float scale[3];
    int relu[3], obf[3], nblk[3];
};

__global__ __launch_bounds__(256) void gemm_bf16(GJobs jb) {
    __shared__ short As[2][64 * 64];   // 16 KB
    __shared__ short Bs[2][64 * 64];   // 16 KB

    int bid = blockIdx.x, j = 0;
    while (j < 2 && bid >= jb.nblk[j]) { bid -= jb.nblk[j]; ++j; }
    const short* __restrict__ A = jb.A[j];
    const short* __restrict__ W = jb.W[j];
    const int N = jb.N[j], K = jb.K[j];
    {
        int nb = jb.nblk[j];
        if ((nb & 7) == 0) bid = (bid & 7) * (nb >> 3) + (bid >> 3);
    }
    const int nbx = N >> 6;
    const int tn = (bid % nbx) * 64;
    const int tm = (bid / nbx) * 64;

    const int tid  = threadIdx.x;
    const int w    = tid >> 6;
    const int l    = tid & 63;
    const int lq   = l & 15;
    const int g    = l >> 4;
    const int wm   = (w >> 1) * 32;
    const int wn   = (w & 1) * 32;
    const int lrow = l >> 3;
    const int lsl  = l & 7;

    f32x4 acc[2][2];
#pragma unroll
    for (int i = 0; i < 2; ++i)
#pragma unroll
        for (int jj = 0; jj < 2; ++jj)
            acc[i][jj] = (f32x4){0.f, 0.f, 0.f, 0.f};

    const int nkt = K >> 6;

#pragma unroll
    for (int i = 0; i < 2; ++i) {
        int row = i * 32 + w * 8 + lrow;
        int slot = lsl ^ (row & 7);
        GLOAD_LDS16(A + (size_t)(tm + row) * K + slot * 8,
                    &As[0][i * 2048 + w * 512]);
        GLOAD_LDS16(W + (size_t)(tn + row) * K + slot * 8,
                    &Bs[0][i * 2048 + w * 512]);
    }

#pragma unroll 2
    for (int kt = 0; kt < nkt; ++kt) {
        const int cur = kt & 1;
        __syncthreads();
        if (kt + 1 < nkt) {
            const int k0n = (kt + 1) * 64;
#pragma unroll
            for (int i = 0; i < 2; ++i) {
                int row = i * 32 + w * 8 + lrow;
                int slot = lsl ^ (row & 7);
                GLOAD_LDS16(A + (size_t)(tm + row) * K + k0n + slot * 8,
                            &As[cur ^ 1][i * 2048 + w * 512]);
                GLOAD_LDS16(W + (size_t)(tn + row) * K + k0n + slot * 8,
                            &Bs[cur ^ 1][i * 2048 + w * 512]);
            }
        }

#pragma unroll
        for (int ks = 0; ks < 2; ++ks) {
            const int sl = ((ks * 4 + g) ^ (lq & 7)) * 8;
            bf16x8 af[2], bfv[2];
#pragma unroll
            for (int i = 0; i < 2; ++i) {
                af[i]  = *(const bf16x8*)&As[cur][(wm + i * 16 + lq) * 64 + sl];
                bfv[i] = *(const bf16x8*)&Bs[cur][(wn + i * 16 + lq) * 64 + sl];
            }
#pragma unroll
            for (int i = 0; i < 2; ++i)
#pragma unroll
                for (int jj = 0; jj < 2; ++jj)
                    acc[i][jj] = __builtin_amdgcn_mfma_f32_16x16x32_bf16(
                        af[i], bfv[jj], acc[i][jj], 0, 0, 0);
        }
    }

    const float* bias  = jb.bias[j];
    const float* resid = jb.resid[j];
    const float scale  = jb.scale[j];
    const int relu = jb.relu[j], obf = jb.obf[j];
#pragma unroll
    for (int i = 0; i < 2; ++i) {
#pragma unroll
        for (int r = 0; r < 4; ++r) {
            int row = tm + wm + i * 16 + g * 4 + r;
#pragma unroll
            for (int jj = 0; jj < 2; ++jj) {
                int col = tn + wn + jj * 16 + lq;
                float v = acc[i][jj][r] * scale;
                if (bias)  v += bias[col];
                if (resid) v += resid[(size_t)row * N + col];
                if (relu)  v = fmaxf(v, 0.f);
                if (obf) ((short*)jb.C[j])[(size_t)row * N + col] = f2bf(v);
                else     ((float*)jb.C[j])[(size_t)row * N + col] = v;
            }
        }
    }
}

// ============================ MFMA flash attention (in-block K-split + XCD affinity) ==
// Best measured attention (round 10): in-block K-split (8 waves; waves w and
// w+4 share a q-tile, alternate key tiles, group-local staging buffers ->
// block-uniform trip counts, no stale-slab race), LDS partial combine, and
// XCD-affine work remap (all 16 q-strips of one bh share lin%8 -> same XCD ->
// the 256 KB K/V stream is L2-resident; 1 MB per XCD for its 4 bh values).
__global__ __launch_bounds__(512) void attn_mfma_kernel(
        const short* __restrict__ Q, const short* __restrict__ K,
        const short* __restrict__ V, short* __restrict__ O,
        int Lq, int Lk, int causal, int qs, int kvs) {
    __shared__ short Kt[2][64 * 64];     // per-group [key][d] swizzled, 8 KB each
    __shared__ short Vt[2][64][72];      // per-group [d][key], 9 KB each
    __shared__ short Pb[8][16][72];      // per-wave P tile, 18 KB (reused as f32 Ox/Lx)

    const int tid  = threadIdx.x;
    const int wave = tid >> 6;           // 0..7
    const int wq4  = wave & 3;           // q-tile within the 64-q strip
    const int tsel = wave >> 2;          // key-parity group
    const int lane = tid & 63;
    const int lq   = lane & 15;
    const int g    = lane >> 4;
    // ---- XCD-affinity remap (bijective on 16x32 grid) ----
    const int lin = (int)(blockIdx.x + blockIdx.y * gridDim.x);
    const int bh  = (lin & 7) * 4 + ((lin >> 3) & 3);
    const int qst = lin >> 5;            // 0..15
    const int b = bh >> 3, h = bh & 7;
    const int qx = causal ? ((int)gridDim.x - 1 - qst) : qst;
    const int q0 = qx * 64 + wq4 * 16;
    const float NEG = -__builtin_inff();

    size_t qoff = (size_t)(b * Lq + q0 + lq) * qs + h * DHEAD;
    bf16x8 qf0 = *(const bf16x8*)(Q + qoff + g * 8);
    bf16x8 qf1 = *(const bf16x8*)(Q + qoff + 32 + g * 8);

    f32x4 o[4] = {{0,0,0,0},{0,0,0,0},{0,0,0,0},{0,0,0,0}};
    f32x4 lacc = {0.f, 0.f, 0.f, 0.f};

    bf16x8 ones;
    {
        short ov = (lq == 0) ? (short)0x3F80 : (short)0;
#pragma unroll
        for (int i = 0; i < 8; ++i) ones[i] = ov;
    }

    const int nkt = causal ? (qx + 1) : (Lk >> 6);   // block-uniform
    const int npair = (nkt + 1) >> 1;
    const int lrow = lane >> 3;
    const int lsl  = lane & 7;
    const int gt = tid & 255;            // group-local tid
    const int va = gt & 31;              // V staging: key pair index
    const int vd = (gt >> 5) * 8;        // V staging: d chunk

#pragma unroll 1
    for (int kp = 0; kp < npair; ++kp) {
        const int t = 2 * kp + tsel;     // this group's key tile
        const int active = (t < nkt);    // wave-uniform
        __syncthreads();
        if (active) {
#pragma unroll
            for (int i = 0; i < 2; ++i) {
                int row = i * 32 + wq4 * 8 + lrow;
                int slot = lsl ^ (row & 7);
                GLOAD_LDS16(K + (size_t)(b * Lk + t * 64 + row) * kvs + h * DHEAD + slot * 8,
                            &Kt[tsel][i * 2048 + wq4 * 512]);
            }
            size_t gb = (size_t)(b * Lk + t * 64 + 2 * va) * kvs + h * DHEAD + vd;
            bf16x8 v0 = *(const bf16x8*)(V + gb);
            bf16x8 v1 = *(const bf16x8*)(V + gb + kvs);
#pragma unroll
            for (int i = 0; i < 8; ++i) {
                unsigned p = (unsigned short)v0[i] | ((unsigned)(unsigned short)v1[i] << 16);
                *(unsigned*)&Vt[tsel][vd + i][2 * va] = p;
            }
        }
        __syncthreads();
        if (!active) continue;

        // ---- S^T = K Q^T ----
        f32x4 s[4];
#pragma unroll
        for (int sub = 0; sub < 4; ++sub) {
            int rr = sub * 16 + lq;
            const int sl0 = ((0 + g) ^ (lq & 7)) * 8;
            const int sl1 = ((4 + g) ^ (lq & 7)) * 8;
            bf16x8 kf0 = *(const bf16x8*)&Kt[tsel][rr * 64 + sl0];
            bf16x8 kf1 = *(const bf16x8*)&Kt[tsel][rr * 64 + sl1];
            f32x4 a = {0.f, 0.f, 0.f, 0.f};
            a = __builtin_amdgcn_mfma_f32_16x16x32_bf16(kf0, qf0, a, 0, 0, 0);
            a = __builtin_amdgcn_mfma_f32_16x16x32_bf16(kf1, qf1, a, 0, 0, 0);
            s[sub] = a;
        }
        if (causal && t == nkt - 1) {
            int qg = q0 + lq;
#pragma unroll
            for (int sub = 0; sub < 4; ++sub) {
#pragma unroll
                for (int r = 0; r < 4; ++r) {
                    int kg = t * 64 + sub * 16 + g * 4 + r;
                    if (kg > qg) s[sub][r] = NEG;
                }
            }
        }

        // ---- exp + packed P write ----
#pragma unroll
        for (int sub = 0; sub < 4; ++sub) {
            short4v p4;
            p4.x = f2bf(__expf(fminf(s[sub][0], 60.f)));
            p4.y = f2bf(__expf(fminf(s[sub][1], 60.f)));
            p4.z = f2bf(__expf(fminf(s[sub][2], 60.f)));
            p4.w = f2bf(__expf(fminf(s[sub][3], 60.f)));
            *(short4v*)&Pb[wave][lq][sub * 16 + g * 4] = p4;
        }
        bf16x8 pf0 = *(const bf16x8*)&Pb[wave][lq][g * 8];
        bf16x8 pf1 = *(const bf16x8*)&Pb[wave][lq][32 + g * 8];

        // ---- O += P V ; l += P @ ones ----
#pragma unroll
        for (int dc = 0; dc < 4; ++dc) {
            bf16x8 vf0 = *(const bf16x8*)&Vt[tsel][dc * 16 + lq][g * 8];
            bf16x8 vf1 = *(const bf16x8*)&Vt[tsel][dc * 16 + lq][32 + g * 8];
            o[dc] = __builtin_amdgcn_mfma_f32_16x16x32_bf16(pf0, vf0, o[dc], 0, 0, 0);
            o[dc] = __builtin_amdgcn_mfma_f32_16x16x32_bf16(pf1, vf1, o[dc], 0, 0, 0);
        }
        lacc = __builtin_amdgcn_mfma_f32_16x16x32_bf16(pf0, ones, lacc, 0, 0, 0);
        lacc = __builtin_amdgcn_mfma_f32_16x16x32_bf16(pf1, ones, lacc, 0, 0, 0);
    }

    // ---- cross-group combine through LDS (Pb retired), then store ----
    float* Ox = (float*)&Pb[0][0][0];      // 4 tiles x 16 q x 64 d = 16 KB
    float* Lx = Ox + 4 * 16 * 64;          // 64 floats
    __syncthreads();                       // all compute/P-reads done
    if (tsel == 1) {
#pragma unroll
        for (int r = 0; r < 4; ++r) {
            int row = g * 4 + r;
            float* dst = Ox + (wq4 * 16 + row) * 64;
            dst[lq]      = o[0][r];
            dst[16 + lq] = o[1][r];
            dst[32 + lq] = o[2][r];
            dst[48 + lq] = o[3][r];
            if (lq == 0) Lx[wq4 * 16 + row] = lacc[r];
        }
    }
    __syncthreads();
    if (tsel == 0) {
#pragma unroll
        for (int r = 0; r < 4; ++r) {
            int row = g * 4 + r;
            float lr = __shfl(lacc[r], g << 4) + Lx[wq4 * 16 + row];
            float inv = 1.f / lr;
            const float* srcx = Ox + (wq4 * 16 + row) * 64;
            size_t ob = (size_t)(b * Lq + q0 + row) * qs + h * DHEAD + lq;
            O[ob + 0]  = f2bf((o[0][r] + srcx[lq])      * inv);
            O[ob + 16] = f2bf((o[1][r] + srcx[16 + lq]) * inv);
            O[ob + 32] = f2bf((o[2][r] + srcx[32 + lq]) * inv);
            O[ob + 48] = f2bf((o[3][r] + srcx[48 + lq]) * inv);
        }
    }
}

// ============================ Launch ============================
static void launch_gemm(GJobs& jb, int njobs, hipStream_t stream) {
    int total = 0;
    for (int i = 0; i < 3; ++i) { if (i >= njobs) jb.nblk[i] = 0; total += jb.nblk[i]; }
    gemm_bf16<<<total, 256, 0, stream>>>(jb);
}

extern "C" void kernel_launch(void* const* d_in, const int* in_sizes, int n_in,
                              void* d_out, int out_size, void* d_ws, size_t ws_size,
                              hipStream_t stream) {
    const float* dec       = (const float*)d_in[0];
    const float* enc       = (const float*)d_in[1];
    const float* slf_Wq    = (const float*)d_in[3];
    const float* slf_Wk    = (const float*)d_in[4];
    const float* slf_Wv    = (const float*)d_in[5];
    const float* slf_Wfc   = (const float*)d_in[6];
    const float* slf_ln_g  = (const float*)d_in[7];
    const float* slf_ln_b  = (const float*)d_in[8];
    const float* enc_Wq    = (const float*)d_in[9];
    const float* enc_Wk    = (const float*)d_in[10];
    const float* enc_Wv    = (const float*)d_in[11];
    const float* enc_Wfc   = (const float*)d_in[12];
    const float* enc_ln_g  = (const float*)d_in[13];
    const float* enc_ln_b  = (const float*)d_in[14];
    const float* ffn_W1    = (const float*)d_in[15];
    const float* ffn_b1    = (const float*)d_in[16];
    const float* ffn_W2    = (const float*)d_in[17];
    const float* ffn_b2    = (const float*)d_in[18];
    const float* ffn_ln_g  = (const float*)d_in[19];
    const float* ffn_ln_b  = (const float*)d_in[20];
    float* out = (float*)d_out;

    const int Bb = 4, L = 1024, M = Bb * L;
    const size_t NE = (size_t)M * DMODEL;          // 2M
    const int WQN = NHEAD * DHEAD * DMODEL;        // 262144
    float* ws = (float*)d_ws;
    float* x1 = ws;
    float* x2 = ws + NE;
    short* kv16e = (short*)x2;     // alias: kv16e consumed (attn2) before x2 written
    short* sb = (short*)(ws + 2 * NE);
    short* dec16 = sb;               sb += NE;
    short* enc16 = sb;               sb += NE;
    short* qn16  = sb;               sb += NE;
    short* q16   = sb;               sb += NE;
    short* ao16  = sb;               sb += NE;
    short* kv16  = sb;               sb += 2 * NE;
    short* h16   = sb;               sb += NE / 2;
    short* wq_s  = sb;               sb += WQN;
    short* wkv_s = sb;               sb += 2 * WQN;
    short* wfc_s = sb;               sb += WQN;
    short* wq_e  = sb;               sb += WQN;
    short* wkv_e = sb;               sb += 2 * WQN;
    short* wfc_e = sb;               sb += WQN;
    short* w1_16 = sb;               sb += 256 * DMODEL;
    short* w2_16 = sb;               sb += DMODEL * 256;

    CvtArgs ca;
    ca.src[0] = dec;     ca.dst[0] = dec16;         ca.n[0] = (int)NE;
    ca.src[1] = enc;     ca.dst[1] = enc16;         ca.n[1] = (int)NE;
    ca.src[2] = slf_Wq;  ca.dst[2] = wq_s;          ca.n[2] = WQN;
    ca.src[3] = slf_Wk;  ca.dst[3] = wkv_s;         ca.n[3] = WQN;
    ca.src[4] = slf_Wv;  ca.dst[4] = wkv_s + WQN;   ca.n[4] = WQN;
    ca.src[5] = slf_Wfc; ca.dst[5] = wfc_s;         ca.n[5] = WQN;
    ca.src[6] = enc_Wq;  ca.dst[6] = wq_e;          ca.n[6] = WQN;
    ca.src[7] = enc_Wk;  ca.dst[7] = wkv_e;         ca.n[7] = WQN;
    ca.src[8] = enc_Wv;  ca.dst[8] = wkv_e + WQN;   ca.n[8] = WQN;
    ca.src[9] = enc_Wfc; ca.dst[9] = wfc_e;         ca.n[9] = WQN;
    ca.src[10] = ffn_W1; ca.dst[10] = w1_16;        ca.n[10] = 256 * DMODEL;
    ca.src[11] = ffn_W2; ca.dst[11] = w2_16;        ca.n[11] = DMODEL * 256;
    {
        int acc = 0;
        for (int t = 0; t < 12; ++t) { ca.start[t] = acc; acc += ca.n[t] / 2048; }
        cvt_kernel<<<acc, 256, 0, stream>>>(ca);
    }

    dim3 attn_grid(L / 64, Bb * NHEAD);
    const int NB512  = (M / 64) * (512 / 64);    // 512
    const int NB1024 = (M / 64) * (1024 / 64);   // 1024
    const int NB256  = (M / 64) * (256 / 64);    // 256

    // ---- LN1 + fused {Q_self, KV_self, KV_cross} ----
    ln_kernel<<<M / 4, 256, 0, stream>>>(dec, slf_ln_g, slf_ln_b, qn16);
    {
        GJobs jb = {};
        jb.A[0] = qn16;  jb.W[0] = wq_s;  jb.C[0] = q16;
        jb.M[0] = M; jb.N[0] = 512;  jb.K[0] = 512; jb.scale[0] = 0.125f;
        jb.obf[0] = 1; jb.nblk[0] = NB512;
        jb.A[1] = dec16; jb.W[1] = wkv_s; jb.C[1] = kv16;
        jb.M[1] = M; jb.N[1] = 1024; jb.K[1] = 512; jb.scale[1] = 1.f;
        jb.obf[1] = 1; jb.nblk[1] = NB1024;
        jb.A[2] = enc16; jb.W[2] = wkv_e; jb.C[2] = kv16e;
        jb.M[2] = M; jb.N[2] = 1024; jb.K[2] = 512; jb.scale[2] = 1.f;
        jb.obf[2] = 1; jb.nblk[2] = NB1024;
        launch_gemm(jb, 3, stream);
    }
    attn_mfma_kernel<<<attn_grid, 512, 0, stream>>>(q16, kv16, kv16 + 512, ao16,
                                                    L, L, 1, DMODEL, 1024);
    {
        GJobs jb = {};
        jb.A[0] = ao16; jb.W[0] = wfc_s; jb.resid[0] = dec; jb.C[0] = x1;
        jb.M[0] = M; jb.N[0] = 512; jb.K[0] = 512; jb.scale[0] = 1.f;
        jb.obf[0] = 0; jb.nblk[0] = NB512;
        launch_gemm(jb, 1, stream);
    }

    // ---- cross attention ----
    ln_kernel<<<M / 4, 256, 0, stream>>>(x1, enc_ln_g, enc_ln_b, qn16);
    {
        GJobs jb = {};
        jb.A[0] = qn16; jb.W[0] = wq_e; jb.C[0] = q16;
        jb.M[0] = M; jb.N[0] = 512; jb.K[0] = 512; jb.scale[0] = 0.125f;
        jb.obf[0] = 1; jb.nblk[0] = NB512;
        launch_gemm(jb, 1, stream);
    }
    attn_mfma_kernel<<<attn_grid, 512, 0, stream>>>(q16, kv16e, kv16e + 512, ao16,
                                                    L, L, 0, DMODEL, 1024);
    {
        GJobs jb = {};
        jb.A[0] = ao16; jb.W[0] = wfc_e; jb.resid[0] = x1; jb.C[0] = x2;
        jb.M[0] = M; jb.N[0] = 512; jb.K[0] = 512; jb.scale[0] = 1.f;
        jb.obf[0] = 0; jb.nblk[0] = NB512;
        launch_gemm(jb, 1, stream);
    }

    // ---- FFN ----
    ln_kernel<<<M / 4, 256, 0, stream>>>(x2, ffn_ln_g, ffn_ln_b, qn16);
    {
        GJobs jb = {};
        jb.A[0] = qn16; jb.W[0] = w1_16; jb.bias[0] = ffn_b1; jb.C[0] = h16;
        jb.M[0] = M; jb.N[0] = 256; jb.K[0] = 512; jb.scale[0] = 1.f;
        jb.relu[0] = 1; jb.obf[0] = 1; jb.nblk[0] = NB256;
        launch_gemm(jb, 1, stream);
    }
    {
        GJobs jb = {};
        jb.A[0] = h16; jb.W[0] = w2_16; jb.bias[0] = ffn_b2; jb.resid[0] = x2;
        jb.C[0] = out;
        jb.M[0] = M; jb.N[0] = 512; jb.K[0] = 256; jb.scale[0] = 1.f;
        jb.obf[0] = 0; jb.nblk[0] = NB512;
        launch_gemm(jb, 1, stream);
    }
}

// Round 14
// 231.802 us; speedup vs baseline: 1.0589x; 1.0057x over previous
//
#include <hip/hip_runtime.h>
#include <hip/hip_bf16.h>
#include <math.h>

#define DMODEL 512
#define NHEAD  8
#define DHEAD  64

typedef __attribute__((ext_vector_type(8))) short bf16x8;
typedef __attribute__((ext_vector_type(4))) float f32x4;
typedef __attribute__((ext_vector_type(4))) short short4v;

static __device__ inline short f2bf(float f) {
    __hip_bfloat16 h = __float2bfloat16(f);
    return *reinterpret_cast<short*>(&h);
}

#define GLOAD_LDS16(gp, lp)                                                      \
    __builtin_amdgcn_global_load_lds(                                            \
        (const __attribute__((address_space(1))) unsigned int*)(gp),             \
        (__attribute__((address_space(3))) unsigned int*)(lp), 16, 0, 0)

// ============================ batched fp32 -> bf16 convert + fused LN1 ================
// Blocks [0, cvtblks) convert; blocks [cvtblks, ...) run LayerNorm on lnX
// (LN1 depends only on kernel inputs, same as cvt -> free dispatch merge;
// LN body is bit-identical to ln_kernel).
struct CvtArgs {
    const float* src[12];
    short*       dst[12];
    int          n[12];
    int          start[12];   // exclusive prefix of per-slot block counts
    const float* lnX;
    const float* lng;
    const float* lnb;
    short*       lnY;
    int          cvtblks;
};

__global__ __launch_bounds__(256) void cvt_kernel(CvtArgs args) {
    int bid = blockIdx.x;
    if (bid >= args.cvtblks) {
        // ---- fused LN1: 4 rows per block, 1 wave per row ----
        int row = (bid - args.cvtblks) * 4 + (threadIdx.x >> 6);
        int tid = threadIdx.x & 63;
        const float* x = args.lnX + (size_t)row * DMODEL;
        float4 a = *(const float4*)(x + tid * 4);
        float4 b = *(const float4*)(x + 256 + tid * 4);
        float sum = a.x + a.y + a.z + a.w + b.x + b.y + b.z + b.w;
        float sq  = a.x*a.x + a.y*a.y + a.z*a.z + a.w*a.w
                  + b.x*b.x + b.y*b.y + b.z*b.z + b.w*b.w;
#pragma unroll
        for (int off = 1; off < 64; off <<= 1) {
            sum += __shfl_xor(sum, off);
            sq  += __shfl_xor(sq, off);
        }
        float mu  = sum * (1.0f / DMODEL);
        float var = sq * (1.0f / DMODEL) - mu * mu;
        float r   = rsqrtf(var + 1e-6f);
        float4 g1 = *(const float4*)(args.lng + tid * 4);
        float4 c1 = *(const float4*)(args.lnb + tid * 4);
        float4 g2 = *(const float4*)(args.lng + 256 + tid * 4);
        float4 c2 = *(const float4*)(args.lnb + 256 + tid * 4);
        short4v y1, y2;
        y1.x = f2bf((a.x - mu) * r * g1.x + c1.x);
        y1.y = f2bf((a.y - mu) * r * g1.y + c1.y);
        y1.z = f2bf((a.z - mu) * r * g1.z + c1.z);
        y1.w = f2bf((a.w - mu) * r * g1.w + c1.w);
        y2.x = f2bf((b.x - mu) * r * g2.x + c2.x);
        y2.y = f2bf((b.y - mu) * r * g2.y + c2.y);
        y2.z = f2bf((b.z - mu) * r * g2.z + c2.z);
        y2.w = f2bf((b.w - mu) * r * g2.w + c2.w);
        short* y = args.lnY + (size_t)row * DMODEL;
        *(short4v*)(y + tid * 4)       = y1;
        *(short4v*)(y + 256 + tid * 4) = y2;
        return;
    }
    int t = 0;
    while (t < 11 && bid >= args.start[t + 1]) ++t;
    int idx = ((bid - args.start[t]) * 256 + threadIdx.x) * 8;
    if (idx >= args.n[t]) return;
    const float* s = args.src[t] + idx;
    float4 a = *(const float4*)s;
    float4 b = *(const float4*)(s + 4);
    bf16x8 o;
    o[0] = f2bf(a.x); o[1] = f2bf(a.y); o[2] = f2bf(a.z); o[3] = f2bf(a.w);
    o[4] = f2bf(b.x); o[5] = f2bf(b.y); o[6] = f2bf(b.z); o[7] = f2bf(b.w);
    *(bf16x8*)(args.dst[t] + idx) = o;
}

// ============================ LayerNorm (fp32 in, bf16 out) ============================
__global__ __launch_bounds__(256) void ln_kernel(const float* __restrict__ X,
                                                 const float* __restrict__ gam,
                                                 const float* __restrict__ bet,
                                                 short* __restrict__ Y) {
    int row = blockIdx.x * 4 + (threadIdx.x >> 6);
    int tid = threadIdx.x & 63;
    const float* x = X + (size_t)row * DMODEL;
    float4 a = *(const float4*)(x + tid * 4);
    float4 b = *(const float4*)(x + 256 + tid * 4);
    float sum = a.x + a.y + a.z + a.w + b.x + b.y + b.z + b.w;
    float sq  = a.x*a.x + a.y*a.y + a.z*a.z + a.w*a.w
              + b.x*b.x + b.y*b.y + b.z*b.z + b.w*b.w;
#pragma unroll
    for (int off = 1; off < 64; off <<= 1) {
        sum += __shfl_xor(sum, off);
        sq  += __shfl_xor(sq, off);
    }
    float mu  = sum * (1.0f / DMODEL);
    float var = sq * (1.0f / DMODEL) - mu * mu;
    float r   = rsqrtf(var + 1e-6f);

    float4 g1 = *(const float4*)(gam + tid * 4);
    float4 c1 = *(const float4*)(bet + tid * 4);
    float4 g2 = *(const float4*)(gam + 256 + tid * 4);
    float4 c2 = *(const float4*)(bet + 256 + tid * 4);
    short4v y1, y2;
    y1.x = f2bf((a.x - mu) * r * g1.x + c1.x);
    y1.y = f2bf((a.y - mu) * r * g1.y + c1.y);
    y1.z = f2bf((a.z - mu) * r * g1.z + c1.z);
    y1.w = f2bf((a.w - mu) * r * g1.w + c1.w);
    y2.x = f2bf((b.x - mu) * r * g2.x + c2.x);
    y2.y = f2bf((b.y - mu) * r * g2.y + c2.y);
    y2.z = f2bf((b.z - mu) * r * g2.z + c2.z);
    y2.w = f2bf((b.w - mu) * r * g2.w + c2.w);
    short* y = Y + (size_t)row * DMODEL;
    *(short4v*)(y + tid * 4)       = y1;
    *(short4v*)(y + 256 + tid * 4) = y2;
}

// ============================ bf16 MFMA GEMM (multi-job) ============================
// Round-6 config (best measured): 64x64 tile, 4 waves 32x32, double-buffered
// LDS 2-phase pipeline + bijective within-job XCD swizzle.
struct GJobs {
    const short* A[3];
    const short* W[3];
    const float* bias[3];
    const float* resid[3];
    void*        C[3];
    int M[3], N[3], K[3];
    float scale[3];
    int relu[3], obf[3], nblk[3];
};

__global__ __launch_bounds__(256) void gemm_bf16(GJobs jb) {
    __shared__ short As[2][64 * 64];   // 16 KB
    __shared__ short Bs[2][64 * 64];   // 16 KB

    int bid = blockIdx.x, j = 0;
    while (j < 2 && bid >= jb.nblk[j]) { bid -= jb.nblk[j]; ++j; }
    const short* __restrict__ A = jb.A[j];
    const short* __restrict__ W = jb.W[j];
    const int N = jb.N[j], K = jb.K[j];
    {
        int nb = jb.nblk[j];
        if ((nb & 7) == 0) bid = (bid & 7) * (nb >> 3) + (bid >> 3);
    }
    const int nbx = N >> 6;
    const int tn = (bid % nbx) * 64;
    const int tm = (bid / nbx) * 64;

    const int tid  = threadIdx.x;
    const int w    = tid >> 6;
    const int l    = tid & 63;
    const int lq   = l & 15;
    const int g    = l >> 4;
    const int wm   = (w >> 1) * 32;
    const int wn   = (w & 1) * 32;
    const int lrow = l >> 3;
    const int lsl  = l & 7;

    f32x4 acc[2][2];
#pragma unroll
    for (int i = 0; i < 2; ++i)
#pragma unroll
        for (int jj = 0; jj < 2; ++jj)
            acc[i][jj] = (f32x4){0.f, 0.f, 0.f, 0.f};

    const int nkt = K >> 6;

#pragma unroll
    for (int i = 0; i < 2; ++i) {
        int row = i * 32 + w * 8 + lrow;
        int slot = lsl ^ (row & 7);
        GLOAD_LDS16(A + (size_t)(tm + row) * K + slot * 8,
                    &As[0][i * 2048 + w * 512]);
        GLOAD_LDS16(W + (size_t)(tn + row) * K + slot * 8,
                    &Bs[0][i * 2048 + w * 512]);
    }

#pragma unroll 2
    for (int kt = 0; kt < nkt; ++kt) {
        const int cur = kt & 1;
        __syncthreads();
        if (kt + 1 < nkt) {
            const int k0n = (kt + 1) * 64;
#pragma unroll
            for (int i = 0; i < 2; ++i) {
                int row = i * 32 + w * 8 + lrow;
                int slot = lsl ^ (row & 7);
                GLOAD_LDS16(A + (size_t)(tm + row) * K + k0n + slot * 8,
                            &As[cur ^ 1][i * 2048 + w * 512]);
                GLOAD_LDS16(W + (size_t)(tn + row) * K + k0n + slot * 8,
                            &Bs[cur ^ 1][i * 2048 + w * 512]);
            }
        }

#pragma unroll
        for (int ks = 0; ks < 2; ++ks) {
            const int sl = ((ks * 4 + g) ^ (lq & 7)) * 8;
            bf16x8 af[2], bfv[2];
#pragma unroll
            for (int i = 0; i < 2; ++i) {
                af[i]  = *(const bf16x8*)&As[cur][(wm + i * 16 + lq) * 64 + sl];
                bfv[i] = *(const bf16x8*)&Bs[cur][(wn + i * 16 + lq) * 64 + sl];
            }
#pragma unroll
            for (int i = 0; i < 2; ++i)
#pragma unroll
                for (int jj = 0; jj < 2; ++jj)
                    acc[i][jj] = __builtin_amdgcn_mfma_f32_16x16x32_bf16(
                        af[i], bfv[jj], acc[i][jj], 0, 0, 0);
        }
    }

    const float* bias  = jb.bias[j];
    const float* resid = jb.resid[j];
    const float scale  = jb.scale[j];
    const int relu = jb.relu[j], obf = jb.obf[j];
#pragma unroll
    for (int i = 0; i < 2; ++i) {
#pragma unroll
        for (int r = 0; r < 4; ++r) {
            int row = tm + wm + i * 16 + g * 4 + r;
#pragma unroll
            for (int jj = 0; jj < 2; ++jj) {
                int col = tn + wn + jj * 16 + lq;
                float v = acc[i][jj][r] * scale;
                if (bias)  v += bias[col];
                if (resid) v += resid[(size_t)row * N + col];
                if (relu)  v = fmaxf(v, 0.f);
                if (obf) ((short*)jb.C[j])[(size_t)row * N + col] = f2bf(v);
                else     ((float*)jb.C[j])[(size_t)row * N + col] = v;
            }
        }
    }
}

// ============================ MFMA flash attention (in-block K-split + XCD affinity) ==
// Best measured attention (round 10): in-block K-split (8 waves; waves w and
// w+4 share a q-tile, alternate key tiles, group-local staging buffers ->
// block-uniform trip counts, no stale-slab race), LDS partial combine, and
// XCD-affine work remap (all 16 q-strips of one bh share lin%8 -> same XCD ->
// the 256 KB K/V stream is L2-resident; 1 MB per XCD for its 4 bh values).
__global__ __launch_bounds__(512) void attn_mfma_kernel(
        const short* __restrict__ Q, const short* __restrict__ K,
        const short* __restrict__ V, short* __restrict__ O,
        int Lq, int Lk, int causal, int qs, int kvs) {
    __shared__ short Kt[2][64 * 64];     // per-group [key][d] swizzled, 8 KB each
    __shared__ short Vt[2][64][72];      // per-group [d][key], 9 KB each
    __shared__ short Pb[8][16][72];      // per-wave P tile, 18 KB (reused as f32 Ox/Lx)

    const int tid  = threadIdx.x;
    const int wave = tid >> 6;           // 0..7
    const int wq4  = wave & 3;           // q-tile within the 64-q strip
    const int tsel = wave >> 2;          // key-parity group
    const int lane = tid & 63;
    const int lq   = lane & 15;
    const int g    = lane >> 4;
    // ---- XCD-affinity remap (bijective on 16x32 grid) ----
    const int lin = (int)(blockIdx.x + blockIdx.y * gridDim.x);
    const int bh  = (lin & 7) * 4 + ((lin >> 3) & 3);
    const int qst = lin >> 5;            // 0..15
    const int b = bh >> 3, h = bh & 7;
    const int qx = causal ? ((int)gridDim.x - 1 - qst) : qst;
    const int q0 = qx * 64 + wq4 * 16;
    const float NEG = -__builtin_inff();

    size_t qoff = (size_t)(b * Lq + q0 + lq) * qs + h * DHEAD;
    bf16x8 qf0 = *(const bf16x8*)(Q + qoff + g * 8);
    bf16x8 qf1 = *(const bf16x8*)(Q + qoff + 32 + g * 8);

    f32x4 o[4] = {{0,0,0,0},{0,0,0,0},{0,0,0,0},{0,0,0,0}};
    f32x4 lacc = {0.f, 0.f, 0.f, 0.f};

    bf16x8 ones;
    {
        short ov = (lq == 0) ? (short)0x3F80 : (short)0;
#pragma unroll
        for (int i = 0; i < 8; ++i) ones[i] = ov;
    }

    const int nkt = causal ? (qx + 1) : (Lk >> 6);   // block-uniform
    const int npair = (nkt + 1) >> 1;
    const int lrow = lane >> 3;
    const int lsl  = lane & 7;
    const int gt = tid & 255;            // group-local tid
    const int va = gt & 31;              // V staging: key pair index
    const int vd = (gt >> 5) * 8;        // V staging: d chunk

#pragma unroll 1
    for (int kp = 0; kp < npair; ++kp) {
        const int t = 2 * kp + tsel;     // this group's key tile
        const int active = (t < nkt);    // wave-uniform
        __syncthreads();
        if (active) {
#pragma unroll
            for (int i = 0; i < 2; ++i) {
                int row = i * 32 + wq4 * 8 + lrow;
                int slot = lsl ^ (row & 7);
                GLOAD_LDS16(K + (size_t)(b * Lk + t * 64 + row) * kvs + h * DHEAD + slot * 8,
                            &Kt[tsel][i * 2048 + wq4 * 512]);
            }
            size_t gb = (size_t)(b * Lk + t * 64 + 2 * va) * kvs + h * DHEAD + vd;
            bf16x8 v0 = *(const bf16x8*)(V + gb);
            bf16x8 v1 = *(const bf16x8*)(V + gb + kvs);
#pragma unroll
            for (int i = 0; i < 8; ++i) {
                unsigned p = (unsigned short)v0[i] | ((unsigned)(unsigned short)v1[i] << 16);
                *(unsigned*)&Vt[tsel][vd + i][2 * va] = p;
            }
        }
        __syncthreads();
        if (!active) continue;

        // ---- S^T = K Q^T ----
        f32x4 s[4];
#pragma unroll
        for (int sub = 0; sub < 4; ++sub) {
            int rr = sub * 16 + lq;
            const int sl0 = ((0 + g) ^ (lq & 7)) * 8;
            const int sl1 = ((4 + g) ^ (lq & 7)) * 8;
            bf16x8 kf0 = *(const bf16x8*)&Kt[tsel][rr * 64 + sl0];
            bf16x8 kf1 = *(const bf16x8*)&Kt[tsel][rr * 64 + sl1];
            f32x4 a = {0.f, 0.f, 0.f, 0.f};
            a = __builtin_amdgcn_mfma_f32_16x16x32_bf16(kf0, qf0, a, 0, 0, 0);
            a = __builtin_amdgcn_mfma_f32_16x16x32_bf16(kf1, qf1, a, 0, 0, 0);
            s[sub] = a;
        }
        if (causal && t == nkt - 1) {
            int qg = q0 + lq;
#pragma unroll
            for (int sub = 0; sub < 4; ++sub) {
#pragma unroll
                for (int r = 0; r < 4; ++r) {
                    int kg = t * 64 + sub * 16 + g * 4 + r;
                    if (kg > qg) s[sub][r] = NEG;
                }
            }
        }

        // ---- exp + packed P write ----
#pragma unroll
        for (int sub = 0; sub < 4; ++sub) {
            short4v p4;
            p4.x = f2bf(__expf(fminf(s[sub][0], 60.f)));
            p4.y = f2bf(__expf(fminf(s[sub][1], 60.f)));
            p4.z = f2bf(__expf(fminf(s[sub][2], 60.f)));
            p4.w = f2bf(__expf(fminf(s[sub][3], 60.f)));
            *(short4v*)&Pb[wave][lq][sub * 16 + g * 4] = p4;
        }
        bf16x8 pf0 = *(const bf16x8*)&Pb[wave][lq][g * 8];
        bf16x8 pf1 = *(const bf16x8*)&Pb[wave][lq][32 + g * 8];

        // ---- O += P V ; l += P @ ones ----
#pragma unroll
        for (int dc = 0; dc < 4; ++dc) {
            bf16x8 vf0 = *(const bf16x8*)&Vt[tsel][dc * 16 + lq][g * 8];
            bf16x8 vf1 = *(const bf16x8*)&Vt[tsel][dc * 16 + lq][32 + g * 8];
            o[dc] = __builtin_amdgcn_mfma_f32_16x16x32_bf16(pf0, vf0, o[dc], 0, 0, 0);
            o[dc] = __builtin_amdgcn_mfma_f32_16x16x32_bf16(pf1, vf1, o[dc], 0, 0, 0);
        }
        lacc = __builtin_amdgcn_mfma_f32_16x16x32_bf16(pf0, ones, lacc, 0, 0, 0);
        lacc = __builtin_amdgcn_mfma_f32_16x16x32_bf16(pf1, ones, lacc, 0, 0, 0);
    }

    // ---- cross-group combine through LDS (Pb retired), then store ----
    float* Ox = (float*)&Pb[0][0][0];      // 4 tiles x 16 q x 64 d = 16 KB
    float* Lx = Ox + 4 * 16 * 64;          // 64 floats
    __syncthreads();                       // all compute/P-reads done
    if (tsel == 1) {
#pragma unroll
        for (int r = 0; r < 4; ++r) {
            int row = g * 4 + r;
            float* dst = Ox + (wq4 * 16 + row) * 64;
            dst[lq]      = o[0][r];
            dst[16 + lq] = o[1][r];
            dst[32 + lq] = o[2][r];
            dst[48 + lq] = o[3][r];
            if (lq == 0) Lx[wq4 * 16 + row] = lacc[r];
        }
    }
    __syncthreads();
    if (tsel == 0) {
#pragma unroll
        for (int r = 0; r < 4; ++r) {
            int row = g * 4 + r;
            float lr = __shfl(lacc[r], g << 4) + Lx[wq4 * 16 + row];
            float inv = 1.f / lr;
            const float* srcx = Ox + (wq4 * 16 + row) * 64;
            size_t ob = (size_t)(b * Lq + q0 + row) * qs + h * DHEAD + lq;
            O[ob + 0]  = f2bf((o[0][r] + srcx[lq])      * inv);
            O[ob + 16] = f2bf((o[1][r] + srcx[16 + lq]) * inv);
            O[ob + 32] = f2bf((o[2][r] + srcx[32 + lq]) * inv);
            O[ob + 48] = f2bf((o[3][r] + srcx[48 + lq]) * inv);
        }
    }
}

// ============================ Launch ============================
static void launch_gemm(GJobs& jb, int njobs, hipStream_t stream) {
    int total = 0;
    for (int i = 0; i < 3; ++i) { if (i >= njobs) jb.nblk[i] = 0; total += jb.nblk[i]; }
    gemm_bf16<<<total, 256, 0, stream>>>(jb);
}

extern "C" void kernel_launch(void* const* d_in, const int* in_sizes, int n_in,
                              void* d_out, int out_size, void* d_ws, size_t ws_size,
                              hipStream_t stream) {
    const float* dec       = (const float*)d_in[0];
    const float* enc       = (const float*)d_in[1];
    const float* slf_Wq    = (const float*)d_in[3];
    const float* slf_Wk    = (const float*)d_in[4];
    const float* slf_Wv    = (const float*)d_in[5];
    const float* slf_Wfc   = (const float*)d_in[6];
    const float* slf_ln_g  = (const float*)d_in[7];
    const float* slf_ln_b  = (const float*)d_in[8];
    const float* enc_Wq    = (const float*)d_in[9];
    const float* enc_Wk    = (const float*)d_in[10];
    const float* enc_Wv    = (const float*)d_in[11];
    const float* enc_Wfc   = (const float*)d_in[12];
    const float* enc_ln_g  = (const float*)d_in[13];
    const float* enc_ln_b  = (const float*)d_in[14];
    const float* ffn_W1    = (const float*)d_in[15];
    const float* ffn_b1    = (const float*)d_in[16];
    const float* ffn_W2    = (const float*)d_in[17];
    const float* ffn_b2    = (const float*)d_in[18];
    const float* ffn_ln_g  = (const float*)d_in[19];
    const float* ffn_ln_b  = (const float*)d_in[20];
    float* out = (float*)d_out;

    const int Bb = 4, L = 1024, M = Bb * L;
    const size_t NE = (size_t)M * DMODEL;          // 2M
    const int WQN = NHEAD * DHEAD * DMODEL;        // 262144
    float* ws = (float*)d_ws;
    float* x1 = ws;
    float* x2 = ws + NE;
    short* kv16e = (short*)x2;     // alias: kv16e consumed (attn2) before x2 written
    short* sb = (short*)(ws + 2 * NE);
    short* dec16 = sb;               sb += NE;
    short* enc16 = sb;               sb += NE;
    short* qn16  = sb;               sb += NE;
    short* q16   = sb;               sb += NE;
    short* ao16  = sb;               sb += NE;
    short* kv16  = sb;               sb += 2 * NE;
    short* h16   = sb;               sb += NE / 2;
    short* wq_s  = sb;               sb += WQN;
    short* wkv_s = sb;               sb += 2 * WQN;
    short* wfc_s = sb;               sb += WQN;
    short* wq_e  = sb;               sb += WQN;
    short* wkv_e = sb;               sb += 2 * WQN;
    short* wfc_e = sb;               sb += WQN;
    short* w1_16 = sb;               sb += 256 * DMODEL;
    short* w2_16 = sb;               sb += DMODEL * 256;

    CvtArgs ca;
    ca.src[0] = dec;     ca.dst[0] = dec16;         ca.n[0] = (int)NE;
    ca.src[1] = enc;     ca.dst[1] = enc16;         ca.n[1] = (int)NE;
    ca.src[2] = slf_Wq;  ca.dst[2] = wq_s;          ca.n[2] = WQN;
    ca.src[3] = slf_Wk;  ca.dst[3] = wkv_s;         ca.n[3] = WQN;
    ca.src[4] = slf_Wv;  ca.dst[4] = wkv_s + WQN;   ca.n[4] = WQN;
    ca.src[5] = slf_Wfc; ca.dst[5] = wfc_s;         ca.n[5] = WQN;
    ca.src[6] = enc_Wq;  ca.dst[6] = wq_e;          ca.n[6] = WQN;
    ca.src[7] = enc_Wk;  ca.dst[7] = wkv_e;         ca.n[7] = WQN;
    ca.src[8] = enc_Wv;  ca.dst[8] = wkv_e + WQN;   ca.n[8] = WQN;
    ca.src[9] = enc_Wfc; ca.dst[9] = wfc_e;         ca.n[9] = WQN;
    ca.src[10] = ffn_W1; ca.dst[10] = w1_16;        ca.n[10] = 256 * DMODEL;
    ca.src[11] = ffn_W2; ca.dst[11] = w2_16;        ca.n[11] = DMODEL * 256;
    ca.lnX = dec; ca.lng = slf_ln_g; ca.lnb = slf_ln_b; ca.lnY = qn16;
    {
        int acc = 0;
        for (int t = 0; t < 12; ++t) { ca.start[t] = acc; acc += ca.n[t] / 2048; }
        ca.cvtblks = acc;
        cvt_kernel<<<acc + M / 4, 256, 0, stream>>>(ca);   // + fused LN1 blocks
    }

    dim3 attn_grid(L / 64, Bb * NHEAD);
    const int NB512  = (M / 64) * (512 / 64);    // 512
    const int NB1024 = (M / 64) * (1024 / 64);   // 1024
    const int NB256  = (M / 64) * (256 / 64);    // 256

    // ---- fused {Q_self, KV_self, KV_cross} (LN1 already done in cvt) ----
    {
        GJobs jb = {};
        jb.A[0] = qn16;  jb.W[0] = wq_s;  jb.C[0] = q16;
        jb.M[0] = M; jb.N[0] = 512;  jb.K[0] = 512; jb.scale[0] = 0.125f;
        jb.obf[0] = 1; jb.nblk[0] = NB512;
        jb.A[1] = dec16; jb.W[1] = wkv_s; jb.C[1] = kv16;
        jb.M[1] = M; jb.N[1] = 1024; jb.K[1] = 512; jb.scale[1] = 1.f;
        jb.obf[1] = 1; jb.nblk[1] = NB1024;
        jb.A[2] = enc16; jb.W[2] = wkv_e; jb.C[2] = kv16e;
        jb.M[2] = M; jb.N[2] = 1024; jb.K[2] = 512; jb.scale[2] = 1.f;
        jb.obf[2] = 1; jb.nblk[2] = NB1024;
        launch_gemm(jb, 3, stream);
    }
    attn_mfma_kernel<<<attn_grid, 512, 0, stream>>>(q16, kv16, kv16 + 512, ao16,
                                                    L, L, 1, DMODEL, 1024);
    {
        GJobs jb = {};
        jb.A[0] = ao16; jb.W[0] = wfc_s; jb.resid[0] = dec; jb.C[0] = x1;
        jb.M[0] = M; jb.N[0] = 512; jb.K[0] = 512; jb.scale[0] = 1.f;
        jb.obf[0] = 0; jb.nblk[0] = NB512;
        launch_gemm(jb, 1, stream);
    }

    // ---- cross attention ----
    ln_kernel<<<M / 4, 256, 0, stream>>>(x1, enc_ln_g, enc_ln_b, qn16);
    {
        GJobs jb = {};
        jb.A[0] = qn16; jb.W[0] = wq_e; jb.C[0] = q16;
        jb.M[0] = M; jb.N[0] = 512; jb.K[0] = 512; jb.scale[0] = 0.125f;
        jb.obf[0] = 1; jb.nblk[0] = NB512;
        launch_gemm(jb, 1, stream);
    }
    attn_mfma_kernel<<<attn_grid, 512, 0, stream>>>(q16, kv16e, kv16e + 512, ao16,
                                                    L, L, 0, DMODEL, 1024);
    {
        GJobs jb = {};
        jb.A[0] = ao16; jb.W[0] = wfc_e; jb.resid[0] = x1; jb.C[0] = x2;
        jb.M[0] = M; jb.N[0] = 512; jb.K[0] = 512; jb.scale[0] = 1.f;
        jb.obf[0] = 0; jb.nblk[0] = NB512;
        launch_gemm(jb, 1, stream);
    }

    // ---- FFN ----
    ln_kernel<<<M / 4, 256, 0, stream>>>(x2, ffn_ln_g, ffn_ln_b, qn16);
    {
        GJobs jb = {};
        jb.A[0] = qn16; jb.W[0] = w1_16; jb.bias[0] = ffn_b1; jb.C[0] = h16;
        jb.M[0] = M; jb.N[0] = 256; jb.K[0] = 512; jb.scale[0] = 1.f;
        jb.relu[0] = 1; jb.obf[0] = 1; jb.nblk[0] = NB256;
        launch_gemm(jb, 1, stream);
    }
    {
        GJobs jb = {};
        jb.A[0] = h16; jb.W[0] = w2_16; jb.bias[0] = ffn_b2; jb.resid[0] = x2;
        jb.C[0] = out;
        jb.M[0] = M; jb.N[0] = 512; jb.K[0] = 256; jb.scale[0] = 1.f;
        jb.obf[0] = 0; jb.nblk[0] = NB512;
        launch_gemm(jb, 1, stream);
    }
}